// Round 7
// baseline (381.749 us; speedup 1.0000x reference)
//
#include <hip/hip_runtime.h>
#include <stdint.h>

typedef float f32x4 __attribute__((ext_vector_type(4)));
typedef __bf16 bf16x8 __attribute__((ext_vector_type(8)));

#define DIM 4608
#define BK 32
#define NT 16
#define WS_L_BYTES (16 * 4 * 512 * 16)  // 512 KiB per l: 16 k-steps x [grp4][col512][8 bf16]

// Entry boundary: counted vmcnt — waits the phase-old DMA (all older than the 2 newest
// B-loads), leaves the just-issued next-tile DMA in flight. NO full drain in the loop.
#define ENTRY()                                         \
  do {                                                  \
    __builtin_amdgcn_sched_barrier(0);                  \
    asm volatile("s_waitcnt vmcnt(2)" ::: "memory");    \
    __builtin_amdgcn_s_barrier();                       \
    __builtin_amdgcn_sched_barrier(0);                  \
  } while (0)

// Frag-visibility boundary: own LDS ops done, barrier. VMEM stays in flight.
#define LGKMBAR()                                       \
  do {                                                  \
    __builtin_amdgcn_sched_barrier(0);                  \
    asm volatile("s_waitcnt lgkmcnt(0)" ::: "memory");  \
    __builtin_amdgcn_s_barrier();                       \
    __builtin_amdgcn_sched_barrier(0);                  \
  } while (0)

// ---------------- prepack: W (fp32) -> ws (bf16, c folded, B-fragment order) ----------------
__global__ __launch_bounds__(256) void prepack(const float* __restrict__ W0,
                                               const float* __restrict__ W1,
                                               const float* __restrict__ W2,
                                               char* __restrict__ ws) {
  int gid = blockIdx.x * 256 + threadIdx.x;  // 3*16*4*512 = 98304 threads
  int col = gid & 511;
  int rest = gid >> 9;
  int grp = rest & 3;
  rest >>= 2;
  int t = rest & 15;
  int l = rest >> 4;
  const float* W = (l == 0) ? W0 : ((l == 1) ? W1 : W2);
  const float c = 0.044194173824159216f;  // 1/sqrt(512) path normalization
  union {
    bf16x8 v;
    uint4 u;
  } pk;
#pragma unroll
  for (int jj = 0; jj < 8; ++jj) {
    float v = W[(t * 32 + grp * 8 + jj) * 512 + col] * c;
    pk.v[jj] = (__bf16)v;
  }
  *(uint4*)(ws + (size_t)l * WS_L_BYTES + ((size_t)((t * 4 + grp) * 512 + col) << 4)) = pk.u;
}

// ---------------- fused per-l GEMM body ----------------
// Block: 256 threads / 4 waves; BZ z-samples x 128 w-cols (wave = 32 cols).
// K=512 in 16 tiles of 32. DMA (global_load_lds, XOR-chunk-swizzled source) -> raw dbuf;
// repack (cvt + b128 frag writes) -> single frag buf; MFMA vs L2-resident B in regs.
// 5 blocks/CU = 5 desynchronized barrier domains; counted-vmcnt entries keep DMA in flight.
template <int D, int BZ, int OFF>
__device__ __forceinline__ void gemm_body(int zc, int j, const float* __restrict__ x1,
                                          const float* __restrict__ x2,
                                          const char* __restrict__ wsl,
                                          float* __restrict__ out,
                                          char* __restrict__ smem) {
  constexpr int BM = BZ * D;               // output rows (z,i) per block
  constexpr int R = BM / 16;               // 16-row MFMA tiles
  constexpr int RAWB = BZ * BK * D * 4;    // raw fp32 tile bytes
  constexpr int CH = RAWB / 16;            // 16B chunks per tile
  constexpr int CPR = BK * D / 4;          // chunks per z-row (multiple of 8)
  constexpr int UNITS = BM * (BK / 8);     // frag 16B units per tile
  constexpr int KD = (CH + 255) / 256;     // DMA rounds
  constexpr int KU = (UNITS + 255) / 256;  // repack rounds

  char* rawbuf = smem;
  char* fragbuf = smem + 2 * RAWB;

  const int tid = threadIdx.x;
  const int z0 = zc * BZ;
  const int cb = j * 128;
  const float* xbase = x1 + (size_t)z0 * DIM + OFF;

  const int lane = tid & 63;
  const int wave = tid >> 6;
  const int llo = lane & 15;
  const int lhi = lane >> 4;

  f32x4 acc[R][2];
#pragma unroll
  for (int rt = 0; rt < R; ++rt)
#pragma unroll
    for (int ct = 0; ct < 2; ++ct) acc[rt][ct] = (f32x4){0.f, 0.f, 0.f, 0.f};

  // ---- DMA: HBM -> raw[t&1]. LDS dest linear; SOURCE pre-swizzled so that LDS chunk c
  // holds global chunk c ^ ((c/CPR)&7) (involution within a z-row; CPR%8==0).
  auto dma = [&](int t) {
    char* ldst = rawbuf + (t & 1) * RAWB;
    const float* xs = xbase + t * (BK * D);
#pragma unroll
    for (int k = 0; k < KD; ++k) {
      int c = tid + k * 256;
      if ((CH % 256 == 0) || (c < CH)) {
        int g = c ^ ((c / CPR) & 7);
        int rowz = g / CPR;
        int off = g - rowz * CPR;
        __builtin_amdgcn_global_load_lds(
            (const __attribute__((address_space(1))) uint32_t*)(xs + (size_t)rowz * DIM + off * 4),
            (__attribute__((address_space(3))) uint32_t*)(ldst + (size_t)c * 16), 16, 0, 0);
      }
    }
  };

  // ---- repack: raw fp32 (stride-D gather, XOR-swizzled addresses) -> frag bf16 units ----
  auto repack = [&](int t) {
    const char* rawt = rawbuf + (t & 1) * RAWB;
#pragma unroll
    for (int s = 0; s < KU; ++s) {
      int u = tid + s * 256;
      if ((UNITS % 256 == 0) || (u < UNITS)) {
        int kg = u / BM;  // 0..3
        int r = u - kg * BM;
        int z = r / D;
        int i = r - z * D;
        bf16x8 v;
#pragma unroll
        for (int jj = 0; jj < 8; ++jj) {
          int fb = (kg * 8 + jj) * D + i;       // float index within z-row
          int b = z * (CPR * 16) + fb * 4;      // byte within tile (unswizzled)
          int lb = ((((b >> 4) ^ (z & 7)) << 4) | (b & 15));
          v[jj] = (__bf16)(*(const float*)(rawt + lb));
        }
        *(bf16x8*)(fragbuf + (size_t)u * 16) = v;
      }
    }
  };

  // ---- B fragments for tile t from L2-resident ws (2 col-tiles per wave) ----
  auto load_b = [&](bf16x8 (&b)[2], int t) {
    const char* wt = wsl + (size_t)t * 32768;
#pragma unroll
    for (int ct = 0; ct < 2; ++ct)
      b[ct] = *(const bf16x8*)(wt + ((lhi * 512 + cb + wave * 32 + ct * 16 + llo) << 4));
  };

  auto compute = [&](bf16x8 (&b)[2]) {
#pragma unroll
    for (int rt = 0; rt < R; ++rt) {
      bf16x8 af = *(const bf16x8*)(fragbuf + ((lhi * BM + rt * 16 + llo) << 4));
#pragma unroll
      for (int ct = 0; ct < 2; ++ct)
        acc[rt][ct] = __builtin_amdgcn_mfma_f32_16x16x32_bf16(af, b[ct], acc[rt][ct], 0, 0, 0);
    }
  };

  // ---- prologue ----
  bf16x8 bE[2], bO[2];
  dma(0);
  __builtin_amdgcn_sched_barrier(0);  // pin: DMA older than B-loads (entry count relies on it)
  load_b(bE, 0);

  // ---- main loop: 8 iters x {E,O} phases; buffer parity & b-reg rotation compile-time ----
  for (int tt = 0; tt < NT / 2; ++tt) {
    const int t = 2 * tt;
    // E phase: raw buf0 holds tile t
    ENTRY();  // drains dma(t); bE(t) stays outstanding (newest 2)
    dma(t + 1);
    __builtin_amdgcn_sched_barrier(0);
    load_b(bO, t + 1);
    repack(t);
    LGKMBAR();
    compute(bE);
    // O phase: raw buf1 holds tile t+1
    ENTRY();  // drains dma(t+1)
    if (tt < NT / 2 - 1) {
      dma(t + 2);
      __builtin_amdgcn_sched_barrier(0);
      load_b(bE, t + 2);
    }
    repack(t + 1);
    LGKMBAR();
    compute(bO);
  }

  // ---- epilogue: C/D layout col=lane&15, row=(lane>>4)*4+reg; fold x2[z] here ----
  float* obase = out + (size_t)z0 * DIM + OFF;
#pragma unroll
  for (int rt = 0; rt < R; ++rt) {
#pragma unroll
    for (int reg = 0; reg < 4; ++reg) {
      int row = rt * 16 + lhi * 4 + reg;
      int z = row / D;
      int i = row - z * D;
      float s = x2[z0 + z];
#pragma unroll
      for (int ct = 0; ct < 2; ++ct) {
        int col = cb + wave * 32 + ct * 16 + llo;
        obase[(size_t)z * DIM + col * D + i] = acc[rt][ct][reg] * s;
      }
    }
  }
}

// Fused: [0,4096) -> l2 (BZ=16), [4096,8192) -> l1 (BZ=16), [8192,9216) -> l0 (BZ=64).
// bid>>2 = z-chunk, bid&3 = col-block (adjacent j share the x1 tile -> L2/L3 reuse).
__global__ __launch_bounds__(256, 5) void gemm_fused(const float* __restrict__ x1,
                                                     const float* __restrict__ x2,
                                                     const char* __restrict__ ws,
                                                     float* __restrict__ out) {
  // LDS: max over l of 2*RAWB + FRAGB = l2: 2*10240 + 5120 = 25600 B -> 5 blocks/CU fits.
  __shared__ __align__(16) char smem[25600];
  int bid = blockIdx.x;
  if (bid < 4096) {
    gemm_body<5, 16, 2048>(bid >> 2, bid & 3, x1, x2, ws + 2 * (size_t)WS_L_BYTES, out, smem);
  } else if (bid < 8192) {
    int b = bid - 4096;
    gemm_body<3, 16, 512>(b >> 2, b & 3, x1, x2, ws + (size_t)WS_L_BYTES, out, smem);
  } else {
    int b = bid - 8192;
    gemm_body<1, 64, 0>(b >> 2, b & 3, x1, x2, ws, out, smem);
  }
}

extern "C" void kernel_launch(void* const* d_in, const int* in_sizes, int n_in,
                              void* d_out, int out_size, void* d_ws, size_t ws_size,
                              hipStream_t stream) {
  const float* x1 = (const float*)d_in[0];
  const float* x2 = (const float*)d_in[1];
  const float* W0 = (const float*)d_in[2];
  const float* W1 = (const float*)d_in[3];
  const float* W2 = (const float*)d_in[4];
  float* out = (float*)d_out;
  char* ws = (char*)d_ws;

  prepack<<<384, 256, 0, stream>>>(W0, W1, W2, ws);
  gemm_fused<<<9216, 256, 0, stream>>>(x1, x2, ws, out);
}